// Round 1
// baseline (109.347 us; speedup 1.0000x reference)
//
#include <hip/hip_runtime.h>
#include <hip/hip_bf16.h>

typedef float  f32x16 __attribute__((ext_vector_type(16)));
typedef short  bf16x8 __attribute__((ext_vector_type(8)));

__device__ __forceinline__ unsigned short f2bf(float x) {
  union { float f; unsigned u; } v; v.f = x;
  return (unsigned short)((v.u + 0x7FFFu + ((v.u >> 16) & 1u)) >> 16);
}

__device__ __forceinline__ float celu1(float x) {
  return x > 0.f ? x : (__expf(x) - 1.f);
}

struct Stage { float4 z[4][2]; float4 a[4][2]; };

__device__ __forceinline__ void issue_stage(Stage& s, const float* __restrict__ zptr,
                                            const float* __restrict__ aptr, int lo, int hi) {
#pragma unroll
  for (int ks = 0; ks < 4; ++ks) {
    const float* pz = zptr + ks * 16 + 8 * hi;
    s.z[ks][0] = *reinterpret_cast<const float4*>(pz);
    s.z[ks][1] = *reinterpret_cast<const float4*>(pz + 4);
    const float* pa = aptr + lo * 64 + ks * 16 + 8 * hi;
    s.a[ks][0] = *reinterpret_cast<const float4*>(pa);
    s.a[ks][1] = *reinterpret_cast<const float4*>(pa + 4);
  }
}

__device__ __forceinline__ bf16x8 to_frag(float4 a, float4 b) {
  bf16x8 r;
  r[0] = (short)f2bf(a.x); r[1] = (short)f2bf(a.y);
  r[2] = (short)f2bf(a.z); r[3] = (short)f2bf(a.w);
  r[4] = (short)f2bf(b.x); r[5] = (short)f2bf(b.y);
  r[6] = (short)f2bf(b.z); r[7] = (short)f2bf(b.w);
  return r;
}

// W^T image in LDS, bf16, XOR-swizzled in 8-element (16B) slots: elem = k ^ ((col&7)<<3)
__device__ __forceinline__ bf16x8 ldsfrag(const unsigned short* w, int S, int col, int k0) {
  return *reinterpret_cast<const bf16x8*>(w + col * S + (k0 ^ ((col & 7) << 3)));
}

__global__ __launch_bounds__(256, 2) void gcu_kernel(
    const float* __restrict__ z, const float* __restrict__ z_,
    const float* __restrict__ Wc, const float* __restrict__ bc,
    const float* __restrict__ Wn, const float* __restrict__ bn,
    const float* __restrict__ Wo, const float* __restrict__ bo,
    float* __restrict__ out, int N) {
  __shared__ __align__(16) unsigned short sWnT[64 * 128];
  __shared__ __align__(16) unsigned short sWcT[64 * 64];
  __shared__ __align__(16) unsigned short sWoT[64 * 128];
  __shared__ __align__(16) unsigned short sVV[4][32 * 128];

  const int tid = threadIdx.x;
  // ---- stage W^T (bf16, swizzled) into LDS ----
  for (int i = tid; i < 128 * 64; i += 256) {
    int c = i & 63, k = i >> 6;                 // src W[k][c], coalesced over c
    int d = c * 128 + (k ^ ((c & 7) << 3));
    sWnT[d] = f2bf(Wn[i]);
    sWoT[d] = f2bf(Wo[i]);
  }
  for (int i = tid; i < 64 * 64; i += 256) {
    int c = i & 63, k = i >> 6;
    sWcT[c * 64 + (k ^ ((c & 7) << 3))] = f2bf(Wc[i]);
  }
  __syncthreads();  // only barrier; before any divergence

  const int wid = tid >> 6, lane = tid & 63;
  const int lo = lane & 31, hi = lane >> 5;
  const int base = (blockIdx.x * 4 + wid) * 32;
  if (base >= N) return;

  unsigned short* vv = &sVV[wid][0];
  const float bn0 = bn[lo], bn1 = bn[32 + lo];
  const float bc0 = bc[lo], bc1 = bc[32 + lo];
  const float bo0 = bo[lo], bo1 = bo[32 + lo];

  auto node_ptrs = [&](int n, const float*& zp, const float*& ap) {
    int nl = min(base + n, N - 1);              // clamp: tail reads valid memory, masked on store
    zp = z + (size_t)nl * 64;
    ap = z_ + (size_t)nl * 2048;
  };

  // per-node: S = (z_n || z_nbr) @ W_nbr, celu, col-sum over 32 nbrs -> vv[n][64..127]
  auto process = [&](const Stage& s, int n) {
    f32x16 acc0{}, acc1{};
#pragma unroll
    for (int ks = 0; ks < 8; ++ks) {
      bf16x8 af = (ks < 4) ? to_frag(s.z[ks][0], s.z[ks][1])
                           : to_frag(s.a[ks - 4][0], s.a[ks - 4][1]);
      bf16x8 b0 = ldsfrag(sWnT, 128, lo,      ks * 16 + 8 * hi);
      bf16x8 b1 = ldsfrag(sWnT, 128, lo + 32, ks * 16 + 8 * hi);
      acc0 = __builtin_amdgcn_mfma_f32_32x32x16_bf16(af, b0, acc0, 0, 0, 0);
      acc1 = __builtin_amdgcn_mfma_f32_32x32x16_bf16(af, b1, acc1, 0, 0, 0);
    }
    float s0 = 0.f, s1 = 0.f;
#pragma unroll
    for (int r = 0; r < 16; ++r) {              // C layout: col=lo, rows spread over regs+hi
      s0 += celu1(acc0[r] + bn0);
      s1 += celu1(acc1[r] + bn1);
    }
    s0 += __shfl_xor(s0, 32, 64);               // add other half's 16 rows
    s1 += __shfl_xor(s1, 32, 64);
    if (hi == 0) {
      vv[n * 128 + ((64 + lo) ^ ((n & 7) << 3))] = f2bf(s0);
      vv[n * 128 + ((96 + lo) ^ ((n & 7) << 3))] = f2bf(s1);
    }
  };

  Stage sA, sB;
  { const float *zp, *ap; node_ptrs(0, zp, ap); issue_stage(sA, zp, ap, lo, hi); }
#pragma unroll 1
  for (int nn = 0; nn < 32; nn += 2) {
    const float *zp, *ap;
    node_ptrs(nn + 1, zp, ap);
    issue_stage(sB, zp, ap, lo, hi);
    process(sA, nn);
    node_ptrs(nn + 2, zp, ap);                  // nn+2==32 clamps into valid memory, discarded
    issue_stage(sA, zp, ap, lo, hi);
    process(sB, nn + 1);
  }

  // ---- cur branch: v = celu(z @ W_cur + b_cur) for the 32 group rows -> vv[r][0..63]
  {
    f32x16 a0{}, a1{};
    int nl = min(base + lo, N - 1);
    const float* zp = z + (size_t)nl * 64;
#pragma unroll
    for (int ks = 0; ks < 4; ++ks) {
      float4 x0 = *reinterpret_cast<const float4*>(zp + ks * 16 + 8 * hi);
      float4 x1 = *reinterpret_cast<const float4*>(zp + ks * 16 + 8 * hi + 4);
      bf16x8 af = to_frag(x0, x1);
      bf16x8 b0 = ldsfrag(sWcT, 64, lo,      ks * 16 + 8 * hi);
      bf16x8 b1 = ldsfrag(sWcT, 64, lo + 32, ks * 16 + 8 * hi);
      a0 = __builtin_amdgcn_mfma_f32_32x32x16_bf16(af, b0, a0, 0, 0, 0);
      a1 = __builtin_amdgcn_mfma_f32_32x32x16_bf16(af, b1, a1, 0, 0, 0);
    }
#pragma unroll
    for (int r = 0; r < 16; ++r) {
      int row = (r & 3) + 8 * (r >> 2) + 4 * hi;
      vv[row * 128 + ( lo        ^ ((row & 7) << 3))] = f2bf(celu1(a0[r] + bc0));
      vv[row * 128 + ((32 + lo)  ^ ((row & 7) << 3))] = f2bf(celu1(a1[r] + bc1));
    }
  }

  // ---- out: dc = (v || v_) @ W_out + b_out ----
  {
    f32x16 a0{}, a1{};
#pragma unroll
    for (int ks = 0; ks < 8; ++ks) {
      bf16x8 af = *reinterpret_cast<const bf16x8*>(
          vv + lo * 128 + ((ks * 16 + 8 * hi) ^ ((lo & 7) << 3)));
      bf16x8 b0 = ldsfrag(sWoT, 128, lo,      ks * 16 + 8 * hi);
      bf16x8 b1 = ldsfrag(sWoT, 128, lo + 32, ks * 16 + 8 * hi);
      a0 = __builtin_amdgcn_mfma_f32_32x32x16_bf16(af, b0, a0, 0, 0, 0);
      a1 = __builtin_amdgcn_mfma_f32_32x32x16_bf16(af, b1, a1, 0, 0, 0);
    }
#pragma unroll
    for (int r = 0; r < 16; ++r) {
      int row = base + (r & 3) + 8 * (r >> 2) + 4 * hi;
      if (row < N) {
        out[(size_t)row * 64 + lo]      = a0[r] + bo0;
        out[(size_t)row * 64 + 32 + lo] = a1[r] + bo1;
      }
    }
  }
}

extern "C" void kernel_launch(void* const* d_in, const int* in_sizes, int n_in,
                              void* d_out, int out_size, void* d_ws, size_t ws_size,
                              hipStream_t stream) {
  const float* z  = (const float*)d_in[0];
  const float* z_ = (const float*)d_in[1];
  const float* Wc = (const float*)d_in[2];
  const float* bc = (const float*)d_in[3];
  const float* Wn = (const float*)d_in[4];
  const float* bn = (const float*)d_in[5];
  const float* Wo = (const float*)d_in[6];
  const float* bo = (const float*)d_in[7];
  float* out = (float*)d_out;
  const int N = in_sizes[0] / 64;          // 50000
  const int tasks = (N + 31) / 32;         // 32 nodes per wave-task
  const int blocks = (tasks + 3) / 4;      // 4 waves per block
  gcu_kernel<<<blocks, 256, 0, stream>>>(z, z_, Wc, bc, Wn, bn, Wo, bo, out, N);
}